// Round 5
// baseline (63.543 us; speedup 1.0000x reference)
//
#include <hip/hip_runtime.h>
#include <math.h>
#include <type_traits>

#define DEV __device__ __forceinline__

DEV float gelu_exact(float x) {
    return 0.5f * x * (1.0f + erff(x * 0.70710678118654752f));
}

DEV float dot4(const float4 a, const float4 b) {
    return a.x * b.x + a.y * b.y + a.z * b.z + a.w * b.w;
}

// ---------------- K1: adjacency bitmask + weight transposes ----------------
// grid = 500 blocks; block 0 additionally writes transposed transformer
// weights into wT so the transformer can load columns as contiguous float4.
// wT layout (floats): [0,256) wqT  [256,512) wkT  [512,768) wvT
//   [768,1024) woT   [1024,1536) f1T   [1536,2048) f2T   [2048,2304) r1T
__global__ __launch_bounds__(512)
void mask_kernel(const float* __restrict__ emb,
                 unsigned long long* __restrict__ maskw,
                 const float* __restrict__ wq, const float* __restrict__ wk,
                 const float* __restrict__ wv, const float* __restrict__ wo,
                 const float* __restrict__ fw1, const float* __restrict__ fw2,
                 const float* __restrict__ rw1,
                 float* __restrict__ wT) {
    const int i = blockIdx.x;
    const int j = threadIdx.x;
    float ei[8], ej[8];
    float si = 0.f, sj = 0.f;
#pragma unroll
    for (int e = 0; e < 8; ++e) { ei[e] = emb[i * 8 + e]; si += ei[e] * ei[e]; }
    const int jj = (j < 500) ? j : 0;
#pragma unroll
    for (int e = 0; e < 8; ++e) { ej[e] = emb[jj * 8 + e]; sj += ej[e] * ej[e]; }
    const float ri = 1.0f / sqrtf(si);
    const float rj = 1.0f / sqrtf(sj);
    float dot = 0.f;
#pragma unroll
    for (int e = 0; e < 8; ++e) dot += (ei[e] * ri) * (ej[e] * rj);
    const bool pred = (j < 500) && (dot > 0.5f);
    unsigned long long m = __ballot(pred);
    if ((threadIdx.x & 63) == 0) maskw[i * 8 + (threadIdx.x >> 6)] = m;

    if (blockIdx.x == 0) {
        for (int t = threadIdx.x; t < 2304; t += 512) {
            float v;
            if (t < 768) {                      // wq/wk/wv 16x16 transpose
                const int base = t >> 8, loc = t & 255;
                const float* src = (base == 0) ? wq : (base == 1) ? wk : wv;
                v = src[(loc & 15) * 16 + (loc >> 4)];
            } else if (t < 1024) {              // woT[e][hd] = wo[hd*16+e]
                const int loc = t - 768;
                v = wo[(loc & 15) * 16 + (loc >> 4)];
            } else if (t < 1536) {              // f1T[f][e] = fw1[e*32+f]
                const int loc = t - 1024;
                v = fw1[(loc & 15) * 32 + (loc >> 4)];
            } else if (t < 2048) {              // f2T[d][ff] = fw2[ff*16+d]
                const int loc = t - 1536;
                v = fw2[(loc & 31) * 16 + (loc >> 5)];
            } else {                            // r1T 16x16 transpose
                const int loc = t - 2048;
                v = rw1[(loc & 15) * 16 + (loc >> 4)];
            }
            wT[t] = v;
        }
    }
}

// ---------------- K2/K3: per-layer GAT ----------------
template <int C, int OUTS, bool PROJ, bool GELU_OUT>
__global__ __launch_bounds__(512)
void gat_kernel(const float* __restrict__ in,
                const float* __restrict__ pw,   // [3,8] (PROJ only)
                const float* __restrict__ pb,   // [8]
                const float* __restrict__ W,    // [8,4,C]
                const float* __restrict__ asrc, // [4,C]
                const float* __restrict__ adst, // [4,C]
                const float* __restrict__ bias, // [4*C]
                const unsigned long long* __restrict__ maskw, // [500][8]
                float* __restrict__ out) {      // [96,500,OUTS]
    using Vec = std::conditional_t<C == 2, float2, float4>;
    const int b = blockIdx.x >> 2;
    const int head = blockIdx.x & 3;
    const int tid = threadIdx.x;
    __shared__ float xh[500 * 9];
    __shared__ Vec h1[500];
    __shared__ float ssrc[500];
    __shared__ float sdst[500];

    if (tid < 500) {
        if constexpr (PROJ) {
            const float* xr = in + ((size_t)b * 500 + tid) * 3;
            const float x0 = xr[0], x1 = xr[1], x2 = xr[2];
#pragma unroll
            for (int e = 0; e < 8; ++e)
                xh[tid * 9 + e] = x0 * pw[e] + x1 * pw[8 + e] + x2 * pw[16 + e] + pb[e];
        } else {
            const float4* xr = (const float4*)(in + ((size_t)b * 500 + tid) * 8);
            const float4 v0 = xr[0], v1 = xr[1];
            xh[tid * 9 + 0] = v0.x; xh[tid * 9 + 1] = v0.y;
            xh[tid * 9 + 2] = v0.z; xh[tid * 9 + 3] = v0.w;
            xh[tid * 9 + 4] = v1.x; xh[tid * 9 + 5] = v1.y;
            xh[tid * 9 + 6] = v1.z; xh[tid * 9 + 7] = v1.w;
        }
    }
    __syncthreads();

    if (tid < 500) {
        float xv[8];
#pragma unroll
        for (int e = 0; e < 8; ++e) xv[e] = xh[tid * 9 + e];
        float acc[C];
#pragma unroll
        for (int c = 0; c < C; ++c) acc[c] = 0.f;
#pragma unroll
        for (int e = 0; e < 8; ++e) {
            const float xe = xv[e];
#pragma unroll
            for (int c = 0; c < C; ++c) acc[c] += xe * W[(e * 4 + head) * C + c];
        }
        float ss = 0.f, sd = 0.f;
#pragma unroll
        for (int c = 0; c < C; ++c) {
            ss += acc[c] * asrc[head * C + c];
            sd += acc[c] * adst[head * C + c];
        }
        Vec hv;
        if constexpr (C == 2) { hv.x = acc[0]; hv.y = acc[1]; }
        else { hv.x = acc[0]; hv.y = acc[1]; hv.z = acc[2]; hv.w = acc[3]; }
        h1[tid] = hv;
        ssrc[tid] = ss;
        sdst[tid] = sd;
    }
    __syncthreads();

    if (tid < 500) {
        const int i = tid;
        const float dd = sdst[i];
        float num[C];
#pragma unroll
        for (int c = 0; c < C; ++c) num[c] = 0.f;
        float den = 0.f;
#pragma unroll 1
        for (int wi = 0; wi < 8; ++wi) {
            unsigned long long m = maskw[i * 8 + wi];
            while (m) {
                const int bit = __ffsll(m) - 1;
                m &= (m - 1);
                const int j = wi * 64 + bit;
                float e = dd + ssrc[j];
                e = (e > 0.f) ? e : 0.2f * e;
                const float w = __expf(e);
                den += w;
                const Vec hj = h1[j];
                if constexpr (C == 2) { num[0] += w * hj.x; num[1] += w * hj.y; }
                else { num[0] += w * hj.x; num[1] += w * hj.y;
                       num[2] += w * hj.z; num[3] += w * hj.w; }
            }
        }
        const float inv = 1.0f / den;
        float* orow = out + ((size_t)b * 500 + i) * OUTS + head * C;
#pragma unroll
        for (int c = 0; c < C; ++c) {
            float v = num[c] * inv + bias[head * C + c];
            if constexpr (GELU_OUT) v = gelu_exact(v);
            orow[c] = v;
        }
    }
}

// ---------------- K4: transformer + pool + regressor ----------------
// grid = 2000 sequences, block = 64 threads (1 wave). Weight columns come
// from the pre-transposed wT as contiguous float4 loads, issued one phase
// ahead so global latency hides under compute.
__global__ __launch_bounds__(64)
void transformer_kernel(const float* __restrict__ tin,  // [2000,24,16]
                        const float* __restrict__ wT,   // transposed weights
                        const float* __restrict__ bq, const float* __restrict__ bk,
                        const float* __restrict__ bv, const float* __restrict__ bo,
                        const float* __restrict__ ln1g, const float* __restrict__ ln1b,
                        const float* __restrict__ ln2g, const float* __restrict__ ln2b,
                        const float* __restrict__ fb1, const float* __restrict__ fb2,
                        const float* __restrict__ rb1, const float* __restrict__ rw2,
                        const float* __restrict__ rb2,
                        float* __restrict__ outp) {
    const int r = blockIdx.x;
    const int lane = threadIdx.x;
    const int d = lane & 15;
    const int srow = lane >> 4;   // 0..3
    const int f = lane & 31;      // FFN1 column
    const int s2 = lane >> 5;     // 0..1
    __shared__ float t0[24][16], qs[24][16], ks[24][16], vs[24][16];
    __shared__ float os[24][16], t1[24][16], hid[24][32], pooled[16];

    // stage t0 + QKV weight columns (contiguous float4 from wT)
    const float4* row4 = (const float4*)(tin + (size_t)r * 384);
    float4* t04 = (float4*)&t0[0][0];
    for (int idx = lane; idx < 96; idx += 64) t04[idx] = row4[idx];
    const float4* wq4 = (const float4*)(wT + 0   + d * 16);
    const float4* wk4 = (const float4*)(wT + 256 + d * 16);
    const float4* wv4 = (const float4*)(wT + 512 + d * 16);
    const float4 q0 = wq4[0], q1 = wq4[1], q2 = wq4[2], q3 = wq4[3];
    const float4 k0 = wk4[0], k1 = wk4[1], k2 = wk4[2], k3 = wk4[3];
    const float4 v0 = wv4[0], v1 = wv4[1], v2 = wv4[2], v3 = wv4[3];
    const float bqv = bq[d], bkv = bk[d], bvv = bv[d];
    __syncthreads();

    // QKV (rows via same-address b128 broadcast)
#pragma unroll
    for (int it = 0; it < 6; ++it) {
        const int s = it * 4 + srow;
        const float4 r0 = *(const float4*)&t0[s][0];
        const float4 r1 = *(const float4*)&t0[s][4];
        const float4 r2 = *(const float4*)&t0[s][8];
        const float4 r3 = *(const float4*)&t0[s][12];
        qs[s][d] = bqv + dot4(r0, q0) + dot4(r1, q1) + dot4(r2, q2) + dot4(r3, q3);
        ks[s][d] = bkv + dot4(r0, k0) + dot4(r1, k1) + dot4(r2, k2) + dot4(r3, k3);
        vs[s][d] = bvv + dot4(r0, v0) + dot4(r1, v1) + dot4(r2, v2) + dot4(r3, v3);
    }
    // issue next phase's weights (out-proj) before the barrier
    const float4* wo4 = (const float4*)(wT + 768 + d * 16);
    const float4 o0 = wo4[0], o1 = wo4[1], o2 = wo4[2], o3 = wo4[3];
    const float bov = bo[d];
    const float g1v = ln1g[d], be1v = ln1b[d];
    __syncthreads();

    // attention: lane = h*24 + s for lane < 48
    if (lane < 48) {
        const int h = lane / 24, s = lane % 24;
        const float4 qa = *(const float4*)&qs[s][h * 8];
        const float4 qb = *(const float4*)&qs[s][h * 8 + 4];
        float sc[24];
        float mx = -1e30f;
#pragma unroll
        for (int t = 0; t < 24; ++t) {
            const float4 ka = *(const float4*)&ks[t][h * 8];
            const float4 kb = *(const float4*)&ks[t][h * 8 + 4];
            const float a = (dot4(qa, ka) + dot4(qb, kb)) * 0.35355339059327373f;
            sc[t] = a;
            mx = fmaxf(mx, a);
        }
        float sum = 0.f;
#pragma unroll
        for (int t = 0; t < 24; ++t) { sc[t] = __expf(sc[t] - mx); sum += sc[t]; }
        const float inv = 1.0f / sum;
        float ax = 0.f, ay = 0.f, az = 0.f, aw = 0.f;
        float bx = 0.f, by = 0.f, bz = 0.f, bw = 0.f;
#pragma unroll
        for (int t = 0; t < 24; ++t) {
            const float4 va = *(const float4*)&vs[t][h * 8];
            const float4 vb = *(const float4*)&vs[t][h * 8 + 4];
            const float w = sc[t];
            ax += w * va.x; ay += w * va.y; az += w * va.z; aw += w * va.w;
            bx += w * vb.x; by += w * vb.y; bz += w * vb.z; bw += w * vb.w;
        }
        float4 ov0 = {ax * inv, ay * inv, az * inv, aw * inv};
        float4 ov1 = {bx * inv, by * inv, bz * inv, bw * inv};
        *(float4*)&os[s][h * 8] = ov0;
        *(float4*)&os[s][h * 8 + 4] = ov1;
    }
    // issue FFN1 weights early
    const float4* f14 = (const float4*)(wT + 1024 + f * 16);
    const float4 fa0 = f14[0], fa1 = f14[1], fa2 = f14[2], fa3 = f14[3];
    const float fb1v = fb1[f];
    __syncthreads();

    // out-proj + residual + LN1
#pragma unroll
    for (int it = 0; it < 6; ++it) {
        const int s = it * 4 + srow;
        const float4 r0 = *(const float4*)&os[s][0];
        const float4 r1 = *(const float4*)&os[s][4];
        const float4 r2 = *(const float4*)&os[s][8];
        const float4 r3 = *(const float4*)&os[s][12];
        const float a = bov + dot4(r0, o0) + dot4(r1, o1) + dot4(r2, o2) + dot4(r3, o3);
        float xv = t0[s][d] + a;
        float sum = xv;
        sum += __shfl_xor(sum, 1); sum += __shfl_xor(sum, 2);
        sum += __shfl_xor(sum, 4); sum += __shfl_xor(sum, 8);
        const float mean = sum * 0.0625f;
        const float df = xv - mean;
        float v2 = df * df;
        v2 += __shfl_xor(v2, 1); v2 += __shfl_xor(v2, 2);
        v2 += __shfl_xor(v2, 4); v2 += __shfl_xor(v2, 8);
        t1[s][d] = df * rsqrtf(v2 * 0.0625f + 1e-3f) * g1v + be1v;
    }
    // issue FFN2 weights early
    const float4* f24 = (const float4*)(wT + 1536 + d * 32);
    const float4 fb0_ = f24[0], fb1_ = f24[1], fb2_ = f24[2], fb3_ = f24[3];
    const float4 fb4_ = f24[4], fb5_ = f24[5], fb6_ = f24[6], fb7_ = f24[7];
    const float fb2v = fb2[d];
    const float g2v = ln2g[d], be2v = ln2b[d];
    __syncthreads();

    // FFN hidden [24][32]
#pragma unroll
    for (int it = 0; it < 12; ++it) {
        const int s = it * 2 + s2;
        const float4 r0 = *(const float4*)&t1[s][0];
        const float4 r1 = *(const float4*)&t1[s][4];
        const float4 r2 = *(const float4*)&t1[s][8];
        const float4 r3 = *(const float4*)&t1[s][12];
        const float a = fb1v + dot4(r0, fa0) + dot4(r1, fa1) + dot4(r2, fa2) + dot4(r3, fa3);
        hid[s][f] = gelu_exact(a);
    }
    // issue regressor weights early
    const float4* r14 = (const float4*)(wT + 2048 + d * 16);
    const float4 ra0 = r14[0], ra1 = r14[1], ra2 = r14[2], ra3 = r14[3];
    const float rb1v = rb1[d], rw2v = rw2[d];
    __syncthreads();

    // FFN out + residual + LN2 + fused mean-pool accumulate
    float pacc = 0.f;
#pragma unroll
    for (int it = 0; it < 6; ++it) {
        const int s = it * 4 + srow;
        const float4 h0 = *(const float4*)&hid[s][0];
        const float4 h1 = *(const float4*)&hid[s][4];
        const float4 h2 = *(const float4*)&hid[s][8];
        const float4 h3 = *(const float4*)&hid[s][12];
        const float4 h4 = *(const float4*)&hid[s][16];
        const float4 h5 = *(const float4*)&hid[s][20];
        const float4 h6 = *(const float4*)&hid[s][24];
        const float4 h7 = *(const float4*)&hid[s][28];
        const float a = fb2v +
            dot4(h0, fb0_) + dot4(h1, fb1_) + dot4(h2, fb2_) + dot4(h3, fb3_) +
            dot4(h4, fb4_) + dot4(h5, fb5_) + dot4(h6, fb6_) + dot4(h7, fb7_);
        float xv = t1[s][d] + a;
        float sum = xv;
        sum += __shfl_xor(sum, 1); sum += __shfl_xor(sum, 2);
        sum += __shfl_xor(sum, 4); sum += __shfl_xor(sum, 8);
        const float mean = sum * 0.0625f;
        const float df = xv - mean;
        float v2 = df * df;
        v2 += __shfl_xor(v2, 1); v2 += __shfl_xor(v2, 2);
        v2 += __shfl_xor(v2, 4); v2 += __shfl_xor(v2, 8);
        pacc += df * rsqrtf(v2 * 0.0625f + 1e-3f) * g2v + be2v;
    }
    pacc += __shfl_xor(pacc, 16);
    pacc += __shfl_xor(pacc, 32);
    if (lane < 16) pooled[lane] = pacc * (1.0f / 24.0f);
    __syncthreads();

    // regressor: gelu(pooled @ rw1 + rb1) @ rw2 + rb2
    float partial = 0.f;
    if (lane < 16) {
        const float4 p0 = *(const float4*)&pooled[0];
        const float4 p1 = *(const float4*)&pooled[4];
        const float4 p2 = *(const float4*)&pooled[8];
        const float4 p3 = *(const float4*)&pooled[12];
        const float a = rb1v + dot4(p0, ra0) + dot4(p1, ra1) + dot4(p2, ra2) + dot4(p3, ra3);
        partial = gelu_exact(a) * rw2v;
    }
    partial += __shfl_xor(partial, 8);
    partial += __shfl_xor(partial, 4);
    partial += __shfl_xor(partial, 2);
    partial += __shfl_xor(partial, 1);
    if (lane == 0) outp[r] = partial + rb2[0];
}

extern "C" void kernel_launch(void* const* d_in, const int* in_sizes, int n_in,
                              void* d_out, int out_size, void* d_ws, size_t ws_size,
                              hipStream_t stream) {
    const float* x      = (const float*)d_in[0];
    const float* emb    = (const float*)d_in[1];
    const float* proj_w = (const float*)d_in[2];
    const float* proj_b = (const float*)d_in[3];
    const float* g1_w   = (const float*)d_in[4];
    const float* g1_as  = (const float*)d_in[5];
    const float* g1_ad  = (const float*)d_in[6];
    const float* g1_b   = (const float*)d_in[7];
    const float* g2_w   = (const float*)d_in[8];
    const float* g2_as  = (const float*)d_in[9];
    const float* g2_ad  = (const float*)d_in[10];
    const float* g2_b   = (const float*)d_in[11];
    const float* wq = (const float*)d_in[12];
    const float* bq = (const float*)d_in[13];
    const float* wk = (const float*)d_in[14];
    const float* bk = (const float*)d_in[15];
    const float* wv = (const float*)d_in[16];
    const float* bv = (const float*)d_in[17];
    const float* wo = (const float*)d_in[18];
    const float* bo = (const float*)d_in[19];
    const float* ln1g = (const float*)d_in[20];
    const float* ln1b = (const float*)d_in[21];
    const float* ln2g = (const float*)d_in[22];
    const float* ln2b = (const float*)d_in[23];
    const float* fw1 = (const float*)d_in[24];
    const float* fb1 = (const float*)d_in[25];
    const float* fw2 = (const float*)d_in[26];
    const float* fb2 = (const float*)d_in[27];
    const float* rw1 = (const float*)d_in[28];
    const float* rb1 = (const float*)d_in[29];
    const float* rw2 = (const float*)d_in[30];
    const float* rb2 = (const float*)d_in[31];

    unsigned long long* maskw = (unsigned long long*)d_ws;       // 32000 B
    float* wT    = (float*)((char*)d_ws + 32768);                // 9216 B (pad 16384)
    float* h_g1  = (float*)((char*)d_ws + 49152);                // 1,536,000 B
    float* t_buf = (float*)((char*)d_ws + 49152 + 1536000);      // 3,072,000 B

    mask_kernel<<<500, 512, 0, stream>>>(emb, maskw, wq, wk, wv, wo, fw1, fw2,
                                         rw1, wT);
    gat_kernel<2, 8, true, true><<<384, 512, 0, stream>>>(
        x, proj_w, proj_b, g1_w, g1_as, g1_ad, g1_b, maskw, h_g1);
    gat_kernel<4, 16, false, false><<<384, 512, 0, stream>>>(
        h_g1, nullptr, nullptr, g2_w, g2_as, g2_ad, g2_b, maskw, t_buf);
    transformer_kernel<<<2000, 64, 0, stream>>>(
        t_buf, wT, bq, bk, bv, bo, ln1g, ln1b, ln2g, ln2b,
        fb1, fb2, rb1, rw2, rb2, (float*)d_out);
}